// Round 2
// baseline (817.619 us; speedup 1.0000x reference)
//
#include <hip/hip_runtime.h>
#include <cmath>

#define NB 512
#define NT 200
#define NIN 88
#define NH 60
#define NZ 100
#define CHUNK 25
#define NCHUNK (NT / CHUNK)

// One block per batch element, 192 threads = 3 waves.
//
// Phase A (RNN): wave0 runs the 200-step serial recurrence
//     h = relu(pre[t] + h @ W_hh.T + bias)
// while waves 1-2 produce pre[t][h] = x_t @ W_ih.T in 25-step chunks,
// double-buffered in LDS (producer runs ~3x faster than the consumer, so the
// serial wave never starves). h is scattered into h_rev at the per-sequence
// reversed position.
//
// Phase B (combiner): 3-way role split, ALL roles overlaying one w[120] array
// so the per-lane register footprint stays ~120 floats (round-1 kept 220 live
// -> scratch spill reloaded every serial step):
//   wave0 lane<60 : w[0:100] = W_zh row  -> hcomb
//   wave1 lane<50 : o=lane    w[0:60]=W_hl row, w[60:120]=W_hs row -> out o
//   wave2 lane<50 : o=50+lane same                                -> out o
__global__ __launch_bounds__(192, 1)
void encoder_kernel(const float* __restrict__ xrev,    // [B][T][IN]
                    const int*   __restrict__ seqlen,  // [B]
                    const float* __restrict__ eps,     // [T][B][Z]
                    const float* __restrict__ W_ih,    // [H][IN]
                    const float* __restrict__ W_hh,    // [H][H]
                    const float* __restrict__ b_ih,    // [H]
                    const float* __restrict__ b_hh,    // [H]
                    const float* __restrict__ h0,      // [H]
                    const float* __restrict__ zq0,     // [Z]
                    const float* __restrict__ W_zh,    // [H][Z]
                    const float* __restrict__ b_zh,    // [H]
                    const float* __restrict__ W_hl,    // [Z][H]
                    const float* __restrict__ b_hl,    // [Z]
                    const float* __restrict__ W_hs,    // [Z][H]
                    const float* __restrict__ b_hs,    // [Z]
                    float* __restrict__ out)           // 3 x [B][T][Z]
{
    __shared__ __align__(16) float h_rev[NT][NH];        // 48000 B
    __shared__ __align__(16) float pre2[2][CHUNK][NH];   // 12000 B
    __shared__ __align__(16) float hbuf[NH];
    __shared__ __align__(16) float zbuf[NZ];
    __shared__ __align__(16) float hcomb[NH];

    const int b    = blockIdx.x;
    const int tid  = threadIdx.x;
    const int wave = tid / 64;
    const int lane = tid & 63;
    const int sl   = seqlen[b];

    // zero h_rev (covers the zero-padded tail t >= sl)
    for (int i = tid; i < NT * NH; i += 192) (&h_rev[0][0])[i] = 0.0f;

    float w[120];           // overlaid weight registers (all phases/roles)
    float bias = 0.0f;

    const float* xb = xrev + (size_t)b * NT * NIN;

    // ---- prologue: wave0 loads W_hh row + h0; waves1/2 fill pre chunk 0 ----
    if (wave == 0) {
        if (lane < NH) {
            const float4* q = reinterpret_cast<const float4*>(W_hh + lane * NH);
#pragma unroll
            for (int k = 0; k < NH / 4; ++k) {
                float4 v = q[k];
                w[4*k+0] = v.x; w[4*k+1] = v.y; w[4*k+2] = v.z; w[4*k+3] = v.w;
            }
            bias = b_ih[lane] + b_hh[lane];
            hbuf[lane] = h0[lane];
        }
    } else {
        const int ptid = tid - 64;  // 0..127
        for (int i = ptid; i < CHUNK * NH; i += 128) {
            int tl = i / NH, h = i % NH;
            const float4* xr = reinterpret_cast<const float4*>(xb + (size_t)tl * NIN);
            const float4* wr = reinterpret_cast<const float4*>(W_ih + h * NIN);
            float a0 = 0.f, a1 = 0.f, a2 = 0.f, a3 = 0.f;
#pragma unroll
            for (int k = 0; k < NIN / 4; ++k) {
                float4 xv = xr[k], wv = wr[k];
                a0 += xv.x * wv.x; a1 += xv.y * wv.y;
                a2 += xv.z * wv.z; a3 += xv.w * wv.w;
            }
            pre2[0][tl][h] = (a0 + a1) + (a2 + a3);
        }
    }
    __syncthreads();

    // ---- Phase A: serial RNN (wave0) || pre-GEMM producer (waves1/2) ----
    for (int c = 0; c < NCHUNK; ++c) {
        if (wave == 0) {
            const int buf = c & 1;
            for (int i = 0; i < CHUNK; ++i) {
                const int t = c * CHUNK + i;
                float a0 = 0.f, a1 = 0.f, a2 = 0.f, a3 = 0.f;
                const float4* h4 = reinterpret_cast<const float4*>(hbuf);
#pragma unroll
                for (int k = 0; k < NH / 4; ++k) {
                    float4 v = h4[k];
                    a0 += v.x * w[4*k+0]; a1 += v.y * w[4*k+1];
                    a2 += v.z * w[4*k+2]; a3 += v.w * w[4*k+3];
                }
                float pv = (lane < NH) ? pre2[buf][i][lane] : 0.0f;
                float hn = fmaxf((a0 + a1) + (a2 + a3) + pv + bias, 0.0f);
                if (lane < NH) {
                    hbuf[lane] = hn;            // single-wave in-order LDS
                    if (t < sl) h_rev[sl - 1 - t][lane] = hn;
                }
            }
        } else if (c + 1 < NCHUNK) {
            const int ptid = tid - 64;
            const float* xc = xb + (size_t)(c + 1) * CHUNK * NIN;
            float* pdst = &pre2[(c + 1) & 1][0][0];
            for (int i = ptid; i < CHUNK * NH; i += 128) {
                int tl = i / NH, h = i % NH;
                const float4* xr = reinterpret_cast<const float4*>(xc + (size_t)tl * NIN);
                const float4* wr = reinterpret_cast<const float4*>(W_ih + h * NIN);
                float a0 = 0.f, a1 = 0.f, a2 = 0.f, a3 = 0.f;
#pragma unroll
                for (int k = 0; k < NIN / 4; ++k) {
                    float4 xv = xr[k], wv = wr[k];
                    a0 += xv.x * wv.x; a1 += xv.y * wv.y;
                    a2 += xv.z * wv.z; a3 += xv.w * wv.w;
                }
                pdst[i] = (a0 + a1) + (a2 + a3);
            }
        }
        __syncthreads();
    }

    // ---- Phase B weight reload (overlay w[]) ----
    float bz = 0.f, bl = 0.f, bs = 0.f;
    int o = 0;
    if (wave == 0) {
        if (lane < NH) {
            const float4* p = reinterpret_cast<const float4*>(W_zh + lane * NZ);
#pragma unroll
            for (int k = 0; k < NZ / 4; ++k) {
                float4 v = p[k];
                w[4*k+0] = v.x; w[4*k+1] = v.y; w[4*k+2] = v.z; w[4*k+3] = v.w;
            }
            bz = b_zh[lane];
        }
    } else if (lane < 50) {
        o = 50 * (wave - 1) + lane;
        const float4* p = reinterpret_cast<const float4*>(W_hl + o * NH);
        const float4* q = reinterpret_cast<const float4*>(W_hs + o * NH);
#pragma unroll
        for (int k = 0; k < NH / 4; ++k) {
            float4 v = p[k];
            w[4*k+0]  = v.x; w[4*k+1]  = v.y; w[4*k+2]  = v.z; w[4*k+3]  = v.w;
            float4 u = q[k];
            w[60+4*k] = u.x; w[61+4*k] = u.y; w[62+4*k] = u.z; w[63+4*k] = u.w;
        }
        bl = b_hl[o];
        bs = b_hs[o];
        zbuf[o] = zq0[o];
    }
    __syncthreads();

    // ---- Phase B: combiner ----
    float* out_z = out;
    float* out_l = out + (size_t)NB * NT * NZ;
    float* out_s = out + (size_t)2 * NB * NT * NZ;
    const float* epsb = eps + (size_t)b * NZ;

    float e_cur = (wave > 0 && lane < 50) ? epsb[o] : 0.0f;

    for (int t = 0; t < NT; ++t) {
        float e_nxt = 0.0f;
        if (wave == 0) {
            float a0 = 0.f, a1 = 0.f, a2 = 0.f, a3 = 0.f;
            const float4* z4 = reinterpret_cast<const float4*>(zbuf);
#pragma unroll
            for (int k = 0; k < NZ / 4; ++k) {
                float4 v = z4[k];
                a0 += v.x * w[4*k+0]; a1 += v.y * w[4*k+1];
                a2 += v.z * w[4*k+2]; a3 += v.w * w[4*k+3];
            }
            if (lane < NH) {
                float a = (a0 + a1) + (a2 + a3) + bz;
                hcomb[lane] = 0.5f * (tanhf(a) + h_rev[t][lane]);
            }
        } else if (t + 1 < NT && lane < 50) {
            e_nxt = epsb[(size_t)(t + 1) * NB * NZ + o];   // overlaps wave0 hcomb
        }
        __syncthreads();  // hcomb visible; zbuf read (wave0) done before overwrite

        if (wave > 0 && lane < 50) {
            float c0 = 0.f, c1 = 0.f, c2 = 0.f, c3 = 0.f;
            float d0 = 0.f, d1 = 0.f, d2 = 0.f, d3 = 0.f;
            const float4* h4 = reinterpret_cast<const float4*>(hcomb);
#pragma unroll
            for (int k = 0; k < NH / 4; ++k) {
                float4 v = h4[k];
                c0 += v.x * w[4*k+0];  c1 += v.y * w[4*k+1];
                c2 += v.z * w[4*k+2];  c3 += v.w * w[4*k+3];
                d0 += v.x * w[60+4*k]; d1 += v.y * w[61+4*k];
                d2 += v.z * w[62+4*k]; d3 += v.w * w[63+4*k];
            }
            float loc = (c0 + c1) + (c2 + c3) + bl;
            float ps  = (d0 + d1) + (d2 + d3) + bs;
            float sc  = fmaxf(ps, 0.0f) + log1pf(expf(-fabsf(ps)));  // stable softplus
            float zv  = loc + sc * e_cur;
            size_t oi = ((size_t)b * NT + t) * NZ + o;
            out_z[oi] = zv;
            out_l[oi] = loc;
            out_s[oi] = sc;
            zbuf[o] = zv;
        }
        e_cur = e_nxt;
        __syncthreads();  // zbuf visible to wave0 for next step
    }
}

extern "C" void kernel_launch(void* const* d_in, const int* in_sizes, int n_in,
                              void* d_out, int out_size, void* d_ws, size_t ws_size,
                              hipStream_t stream) {
    const float* xrev   = (const float*)d_in[1];
    const int*   seqlen = (const int*)  d_in[3];
    const float* eps    = (const float*)d_in[4];
    const float* W_ih   = (const float*)d_in[5];
    const float* W_hh   = (const float*)d_in[6];
    const float* b_ih   = (const float*)d_in[7];
    const float* b_hh   = (const float*)d_in[8];
    const float* h0     = (const float*)d_in[9];
    const float* zq0    = (const float*)d_in[10];
    const float* W_zh   = (const float*)d_in[11];
    const float* b_zh   = (const float*)d_in[12];
    const float* W_hl   = (const float*)d_in[13];
    const float* b_hl   = (const float*)d_in[14];
    const float* W_hs   = (const float*)d_in[15];
    const float* b_hs   = (const float*)d_in[16];
    float* out = (float*)d_out;

    encoder_kernel<<<NB, 192, 0, stream>>>(xrev, seqlen, eps,
                                           W_ih, W_hh, b_ih, b_hh, h0, zq0,
                                           W_zh, b_zh, W_hl, b_hl, W_hs, b_hs,
                                           out);
}

// Round 3
// 795.034 us; speedup vs baseline: 1.0284x; 1.0284x over previous
//
#include <hip/hip_runtime.h>
#include <cmath>

#define NB 512
#define NT 200
#define NIN 88
#define NH 60
#define NZ 100

__device__ __forceinline__ float fast_tanh(float x) {
    float cx = fminf(fmaxf(x, -10.f), 10.f);
    float e  = __expf(2.f * cx);
    return (e - 1.f) * __builtin_amdgcn_rcpf(e + 1.f);
}
__device__ __forceinline__ float fast_softplus(float x) {
    return fmaxf(x, 0.f) + __logf(1.f + __expf(-fabsf(x)));
}

// ---------------------------------------------------------------------------
// Kernel 1: pre[b][t][h] = x_rev[b][t] . W_ih[h] + b_ih[h] + b_hh[h]
// Fully parallel; takes the input projection off the serial critical path.
// ---------------------------------------------------------------------------
__global__ __launch_bounds__(256, 1)
void pre_kernel(const float* __restrict__ xrev, const float* __restrict__ W_ih,
                const float* __restrict__ b_ih, const float* __restrict__ b_hh,
                float* __restrict__ pre)
{
    const int b = blockIdx.x;
    const float* xb = xrev + (size_t)b * NT * NIN;
    float* pb = pre + (size_t)b * NT * NH;
    for (int i = threadIdx.x; i < NT * NH; i += 256) {
        const int t = i / NH, h = i - t * NH;
        const float4* xr = reinterpret_cast<const float4*>(xb + (size_t)t * NIN);
        const float4* wr = reinterpret_cast<const float4*>(W_ih + h * NIN);
        float a0 = 0.f, a1 = 0.f, a2 = 0.f, a3 = 0.f;
        float c0 = 0.f, c1 = 0.f, c2 = 0.f, c3 = 0.f;
#pragma unroll
        for (int k = 0; k < 11; ++k) {
            float4 x = xr[k], w = wr[k];
            a0 += x.x * w.x; a1 += x.y * w.y; a2 += x.z * w.z; a3 += x.w * w.w;
        }
#pragma unroll
        for (int k = 11; k < 22; ++k) {
            float4 x = xr[k], w = wr[k];
            c0 += x.x * w.x; c1 += x.y * w.y; c2 += x.z * w.z; c3 += x.w * w.w;
        }
        pb[i] = ((a0 + c0) + (a1 + c1)) + ((a2 + c2) + (a3 + c3)) + b_ih[h] + b_hh[h];
    }
}

// ---------------------------------------------------------------------------
// Kernel 2: serial encoder. One block per batch element, 192 threads = 3 waves.
// Phase A: wave0 runs h = relu(pre[t] + h@W_hh.T) (no barriers, 60-FMA step);
//          if pre==nullptr, falls back to in-kernel x projection (r1 style).
// Phase B: 3-wave role split over one overlaid w[] array (no spills):
//   wave0 lane<60: w[0:100]=W_zh row -> hcomb;  waves1/2 lane<50: o=50*(wv-1)+l,
//   w[0:60]=W_hl row, w[60:120]=W_hs row -> loc/scale/z for output o.
// ---------------------------------------------------------------------------
__global__ __launch_bounds__(192, 1)
void encoder_kernel(const float* __restrict__ xrev,    // [B][T][IN]
                    const int*   __restrict__ seqlen,  // [B]
                    const float* __restrict__ eps,     // [T][B][Z]
                    const float* __restrict__ W_ih,    // [H][IN]
                    const float* __restrict__ W_hh,    // [H][H]
                    const float* __restrict__ b_ih,    // [H]
                    const float* __restrict__ b_hh,    // [H]
                    const float* __restrict__ h0,      // [H]
                    const float* __restrict__ zq0,     // [Z]
                    const float* __restrict__ W_zh,    // [H][Z]
                    const float* __restrict__ b_zh,    // [H]
                    const float* __restrict__ W_hl,    // [Z][H]
                    const float* __restrict__ b_hl,    // [Z]
                    const float* __restrict__ W_hs,    // [Z][H]
                    const float* __restrict__ b_hs,    // [Z]
                    const float* __restrict__ pre,     // [B][T][H] or nullptr
                    float* __restrict__ out)           // 3 x [B][T][Z]
{
    __shared__ __align__(16) float h_rev[NT][NH];   // 48000 B
    __shared__ __align__(16) float xbuf[NIN];       // fallback staging
    __shared__ __align__(16) float hbuf[NH];
    __shared__ __align__(16) float zbuf[NZ];
    __shared__ __align__(16) float hcomb[NH];

    const int b    = blockIdx.x;
    const int tid  = threadIdx.x;
    const int wave = tid / 64;
    const int lane = tid & 63;
    const int sl   = seqlen[b];

    for (int i = tid; i < NT * NH; i += 192) (&h_rev[0][0])[i] = 0.0f;

    float w[148];        // overlaid weights: A-pre {Whh:0..60}; A-fallback
                         // {Wih:0..88, Whh:88..148}; B-wave0 {Wzh:0..100};
                         // B-waves1/2 {Whl:0..60, Whs:60..120}
    float bias = 0.0f;
    float bz = 0.f, bl = 0.f, bs = 0.f;
    int   o  = 0;
    const bool olane = (wave > 0) && (lane < 50);
    const float* epsb = eps + (size_t)b * NZ;
    float e_cur = 0.f;

    // ---- per-role loads (waves1/2 load phase-B state during wave0's setup) --
    if (wave == 0) {
        if (lane < NH) {
            if (pre) {
                const float4* q = reinterpret_cast<const float4*>(W_hh + lane * NH);
#pragma unroll
                for (int k = 0; k < NH / 4; ++k) {
                    float4 v = q[k];
                    w[4*k+0] = v.x; w[4*k+1] = v.y; w[4*k+2] = v.z; w[4*k+3] = v.w;
                }
            } else {
                const float4* p = reinterpret_cast<const float4*>(W_ih + lane * NIN);
#pragma unroll
                for (int k = 0; k < NIN / 4; ++k) {
                    float4 v = p[k];
                    w[4*k+0] = v.x; w[4*k+1] = v.y; w[4*k+2] = v.z; w[4*k+3] = v.w;
                }
                const float4* q = reinterpret_cast<const float4*>(W_hh + lane * NH);
#pragma unroll
                for (int k = 0; k < NH / 4; ++k) {
                    float4 v = q[k];
                    w[88+4*k+0] = v.x; w[88+4*k+1] = v.y; w[88+4*k+2] = v.z; w[88+4*k+3] = v.w;
                }
                bias = b_ih[lane] + b_hh[lane];
            }
            hbuf[lane] = h0[lane];
        }
    } else if (olane) {
        o = 50 * (wave - 1) + lane;
        const float4* p = reinterpret_cast<const float4*>(W_hl + o * NH);
        const float4* q = reinterpret_cast<const float4*>(W_hs + o * NH);
#pragma unroll
        for (int k = 0; k < NH / 4; ++k) {
            float4 v = p[k];
            w[4*k+0]  = v.x; w[4*k+1]  = v.y; w[4*k+2]  = v.z; w[4*k+3]  = v.w;
            float4 u = q[k];
            w[60+4*k] = u.x; w[61+4*k] = u.y; w[62+4*k] = u.z; w[63+4*k] = u.w;
        }
        bl = b_hl[o];
        bs = b_hs[o];
        zbuf[o] = zq0[o];
        e_cur = epsb[o];
    }
    __syncthreads();   // h_rev zeroed; hbuf/zbuf init visible

    // ---------------- Phase A: serial RNN (wave0 only, no barriers) ----------
    if (wave == 0) {
        if (pre) {
            const float* pb = pre + (size_t)b * NT * NH;
            float pcur = (lane < NH) ? pb[lane] : 0.f;
            for (int t = 0; t < NT; ++t) {
                float pnxt = (t + 1 < NT && lane < NH) ? pb[(size_t)(t+1)*NH + lane] : 0.f;
                const float4* h4 = reinterpret_cast<const float4*>(hbuf);
                float a0=0.f,a1=0.f,a2=0.f,a3=0.f, c0=0.f,c1=0.f,c2=0.f,c3=0.f;
#pragma unroll
                for (int k = 0; k < 8; ++k) {
                    float4 v = h4[k];
                    a0 += v.x*w[4*k+0]; a1 += v.y*w[4*k+1];
                    a2 += v.z*w[4*k+2]; a3 += v.w*w[4*k+3];
                }
#pragma unroll
                for (int k = 8; k < 15; ++k) {
                    float4 v = h4[k];
                    c0 += v.x*w[4*k+0]; c1 += v.y*w[4*k+1];
                    c2 += v.z*w[4*k+2]; c3 += v.w*w[4*k+3];
                }
                float hn = fmaxf(((a0+c0)+(a1+c1)) + ((a2+c2)+(a3+c3)) + pcur, 0.f);
                if (lane < NH) {
                    hbuf[lane] = hn;
                    if (t < sl) h_rev[sl - 1 - t][lane] = hn;
                }
                pcur = pnxt;
            }
        } else {
            // fallback: in-kernel x projection (round-1 structure)
            const float* xb = xrev + (size_t)b * NT * NIN;
            float xa = xb[lane];
            float xc = (lane < NIN - 64) ? xb[64 + lane] : 0.f;
            for (int t = 0; t < NT; ++t) {
                xbuf[lane] = xa;
                if (lane < NIN - 64) xbuf[64 + lane] = xc;
                if (t + 1 < NT) {
                    xa = xb[(size_t)(t+1)*NIN + lane];
                    xc = (lane < NIN - 64) ? xb[(size_t)(t+1)*NIN + 64 + lane] : 0.f;
                }
                float a0=0.f,a1=0.f,a2=0.f,a3=0.f;
                const float4* x4 = reinterpret_cast<const float4*>(xbuf);
#pragma unroll
                for (int k = 0; k < NIN / 4; ++k) {
                    float4 v = x4[k];
                    a0 += v.x*w[4*k+0]; a1 += v.y*w[4*k+1];
                    a2 += v.z*w[4*k+2]; a3 += v.w*w[4*k+3];
                }
                const float4* h4 = reinterpret_cast<const float4*>(hbuf);
#pragma unroll
                for (int k = 0; k < NH / 4; ++k) {
                    float4 v = h4[k];
                    a0 += v.x*w[88+4*k+0]; a1 += v.y*w[88+4*k+1];
                    a2 += v.z*w[88+4*k+2]; a3 += v.w*w[88+4*k+3];
                }
                float hn = fmaxf((a0+a1)+(a2+a3) + bias, 0.f);
                if (lane < NH) {
                    hbuf[lane] = hn;
                    if (t < sl) h_rev[sl - 1 - t][lane] = hn;
                }
            }
        }
        // reload overlay for phase B: W_zh row
        if (lane < NH) {
            const float4* p = reinterpret_cast<const float4*>(W_zh + lane * NZ);
#pragma unroll
            for (int k = 0; k < NZ / 4; ++k) {
                float4 v = p[k];
                w[4*k+0] = v.x; w[4*k+1] = v.y; w[4*k+2] = v.z; w[4*k+3] = v.w;
            }
            bz = b_zh[lane];
        }
    }
    __syncthreads();   // h_rev complete

    // ---------------- Phase B: combiner ----------------
    float* out_z = out;
    float* out_l = out + (size_t)NB * NT * NZ;
    float* out_s = out + (size_t)2 * NB * NT * NZ;

    for (int t = 0; t < NT; ++t) {
        float e_nxt = 0.f;
        if (wave == 0) {
            float hr = (lane < NH) ? h_rev[t][lane] : 0.f;   // off critical path
            const float4* z4 = reinterpret_cast<const float4*>(zbuf);
            float a0=0.f,a1=0.f,a2=0.f,a3=0.f, c0=0.f,c1=0.f,c2=0.f,c3=0.f;
#pragma unroll
            for (int k = 0; k < 13; ++k) {
                float4 v = z4[k];
                a0 += v.x*w[4*k+0]; a1 += v.y*w[4*k+1];
                a2 += v.z*w[4*k+2]; a3 += v.w*w[4*k+3];
            }
#pragma unroll
            for (int k = 13; k < 25; ++k) {
                float4 v = z4[k];
                c0 += v.x*w[4*k+0]; c1 += v.y*w[4*k+1];
                c2 += v.z*w[4*k+2]; c3 += v.w*w[4*k+3];
            }
            if (lane < NH) {
                float a = ((a0+c0)+(a1+c1)) + ((a2+c2)+(a3+c3)) + bz;
                hcomb[lane] = 0.5f * (fast_tanh(a) + hr);
            }
        } else if (olane && t + 1 < NT) {
            e_nxt = epsb[(size_t)(t + 1) * NB * NZ + o];  // overlaps wave0 compute
        }
        __syncthreads();  // hcomb ready; wave0's zbuf reads done

        if (olane) {
            const float4* h4 = reinterpret_cast<const float4*>(hcomb);
            float c0=0.f,c1=0.f,c2=0.f,c3=0.f, c4=0.f,c5=0.f,c6=0.f,c7=0.f;
            float d0=0.f,d1=0.f,d2=0.f,d3=0.f, d4=0.f,d5=0.f,d6=0.f,d7=0.f;
#pragma unroll
            for (int k = 0; k < 8; ++k) {
                float4 v = h4[k];
                c0 += v.x*w[4*k+0];  c1 += v.y*w[4*k+1];
                c2 += v.z*w[4*k+2];  c3 += v.w*w[4*k+3];
                d0 += v.x*w[60+4*k]; d1 += v.y*w[61+4*k];
                d2 += v.z*w[62+4*k]; d3 += v.w*w[63+4*k];
            }
#pragma unroll
            for (int k = 8; k < 15; ++k) {
                float4 v = h4[k];
                c4 += v.x*w[4*k+0];  c5 += v.y*w[4*k+1];
                c6 += v.z*w[4*k+2];  c7 += v.w*w[4*k+3];
                d4 += v.x*w[60+4*k]; d5 += v.y*w[61+4*k];
                d6 += v.z*w[62+4*k]; d7 += v.w*w[63+4*k];
            }
            float loc = ((c0+c4)+(c1+c5)) + ((c2+c6)+(c3+c7)) + bl;
            float ps  = ((d0+d4)+(d1+d5)) + ((d2+d6)+(d3+d7)) + bs;
            float sc  = fast_softplus(ps);
            float zv  = loc + sc * e_cur;
            size_t oi = ((size_t)b * NT + t) * NZ + o;
            out_z[oi] = zv;
            out_l[oi] = loc;
            out_s[oi] = sc;
            zbuf[o] = zv;
        }
        e_cur = e_nxt;
        __syncthreads();  // zbuf ready for next step
    }
}

extern "C" void kernel_launch(void* const* d_in, const int* in_sizes, int n_in,
                              void* d_out, int out_size, void* d_ws, size_t ws_size,
                              hipStream_t stream) {
    const float* xrev   = (const float*)d_in[1];
    const int*   seqlen = (const int*)  d_in[3];
    const float* eps    = (const float*)d_in[4];
    const float* W_ih   = (const float*)d_in[5];
    const float* W_hh   = (const float*)d_in[6];
    const float* b_ih   = (const float*)d_in[7];
    const float* b_hh   = (const float*)d_in[8];
    const float* h0     = (const float*)d_in[9];
    const float* zq0    = (const float*)d_in[10];
    const float* W_zh   = (const float*)d_in[11];
    const float* b_zh   = (const float*)d_in[12];
    const float* W_hl   = (const float*)d_in[13];
    const float* b_hl   = (const float*)d_in[14];
    const float* W_hs   = (const float*)d_in[15];
    const float* b_hs   = (const float*)d_in[16];
    float* out = (float*)d_out;

    const size_t pre_bytes = (size_t)NB * NT * NH * sizeof(float);
    const bool use_pre = (ws_size >= pre_bytes);
    if (use_pre) {
        pre_kernel<<<NB, 256, 0, stream>>>(xrev, W_ih, b_ih, b_hh, (float*)d_ws);
    }
    encoder_kernel<<<NB, 192, 0, stream>>>(xrev, seqlen, eps,
                                           W_ih, W_hh, b_ih, b_hh, h0, zq0,
                                           W_zh, b_zh, W_hl, b_hl, W_hs, b_hs,
                                           use_pre ? (const float*)d_ws : nullptr,
                                           out);
}

// Round 4
// 685.418 us; speedup vs baseline: 1.1929x; 1.1599x over previous
//
#include <hip/hip_runtime.h>
#include <cmath>

#define NB 512
#define NT 200
#define NIN 88
#define NH 60
#define NZ 100

__device__ __forceinline__ float bcast(float v, int j) {
    return __int_as_float(__builtin_amdgcn_readlane(__float_as_int(v), j));
}
__device__ __forceinline__ float fast_tanh(float x) {
    float cx = fminf(fmaxf(x, -10.f), 10.f);
    float e  = __expf(2.f * cx);
    return (e - 1.f) * __builtin_amdgcn_rcpf(e + 1.f);
}
__device__ __forceinline__ float fast_softplus(float x) {
    return fmaxf(x, 0.f) + __logf(1.f + __expf(-fabsf(x)));
}

// ---------------------------------------------------------------------------
// Kernel 1: ReLU RNN, one wave per batch element. h lives one-per-lane in
// registers; dot products use readlane broadcasts (zero LDS, zero barriers).
// Writes h_rev[b][sl-1-t][:] rows straight to global ws (off dep chain).
// ---------------------------------------------------------------------------
__global__ __launch_bounds__(64, 1)
void rnn_kernel(const float* __restrict__ xrev,   // [B][T][IN]
                const int*   __restrict__ seqlen, // [B]
                const float* __restrict__ W_ih,   // [H][IN]
                const float* __restrict__ W_hh,   // [H][H]
                const float* __restrict__ b_ih,
                const float* __restrict__ b_hh,
                const float* __restrict__ h0,
                float* __restrict__ hrev)         // [B][T][H] (ws)
{
    const int b    = blockIdx.x;
    const int lane = threadIdx.x;
    const int sl   = seqlen[b];
    float* hb = hrev + (size_t)b * NT * NH;

    // zero the padded tail rows [sl, NT)
    for (int i = lane; i < (NT - sl) * NH; i += 64)
        hb[(size_t)sl * NH + i] = 0.0f;

    float wih[NIN], whh[NH];
    float bias = 0.f, hn = 0.f;
    if (lane < NH) {
        const float4* p = reinterpret_cast<const float4*>(W_ih + lane * NIN);
#pragma unroll
        for (int k = 0; k < NIN / 4; ++k) {
            float4 v = p[k];
            wih[4*k+0] = v.x; wih[4*k+1] = v.y; wih[4*k+2] = v.z; wih[4*k+3] = v.w;
        }
        const float4* q = reinterpret_cast<const float4*>(W_hh + lane * NH);
#pragma unroll
        for (int k = 0; k < NH / 4; ++k) {
            float4 v = q[k];
            whh[4*k+0] = v.x; whh[4*k+1] = v.y; whh[4*k+2] = v.z; whh[4*k+3] = v.w;
        }
        bias = b_ih[lane] + b_hh[lane];
        hn   = h0[lane];
    } else {
#pragma unroll
        for (int k = 0; k < NIN; ++k) wih[k] = 0.f;
#pragma unroll
        for (int k = 0; k < NH; ++k)  whh[k] = 0.f;
    }

    const float* xb = xrev + (size_t)b * NT * NIN;
    float xa = xb[lane];                                  // x[t][0:64]
    float xc = (lane < NIN - 64) ? xb[64 + lane] : 0.f;   // x[t][64:88]

    for (int t = 0; t < NT; ++t) {
        float xa_n = 0.f, xc_n = 0.f;
        if (t + 1 < NT) {
            xa_n = xb[(size_t)(t + 1) * NIN + lane];
            if (lane < NIN - 64) xc_n = xb[(size_t)(t + 1) * NIN + 64 + lane];
        }
        float a0 = bias, a1 = 0.f, a2 = 0.f, a3 = 0.f;
#pragma unroll
        for (int k = 0; k < 64; k += 4) {
            a0 = fmaf(bcast(xa, k+0), wih[k+0], a0);
            a1 = fmaf(bcast(xa, k+1), wih[k+1], a1);
            a2 = fmaf(bcast(xa, k+2), wih[k+2], a2);
            a3 = fmaf(bcast(xa, k+3), wih[k+3], a3);
        }
#pragma unroll
        for (int k = 0; k < 24; k += 4) {
            a0 = fmaf(bcast(xc, k+0), wih[64+k+0], a0);
            a1 = fmaf(bcast(xc, k+1), wih[64+k+1], a1);
            a2 = fmaf(bcast(xc, k+2), wih[64+k+2], a2);
            a3 = fmaf(bcast(xc, k+3), wih[64+k+3], a3);
        }
#pragma unroll
        for (int j = 0; j < NH; j += 4) {
            a0 = fmaf(bcast(hn, j+0), whh[j+0], a0);
            a1 = fmaf(bcast(hn, j+1), whh[j+1], a1);
            a2 = fmaf(bcast(hn, j+2), whh[j+2], a2);
            a3 = fmaf(bcast(hn, j+3), whh[j+3], a3);
        }
        hn = fmaxf((a0 + a1) + (a2 + a3), 0.f);
        if (lane < NH && t < sl)
            hb[(size_t)(sl - 1 - t) * NH + lane] = hn;    // fire-and-forget
        xa = xa_n; xc = xc_n;
    }
}

// ---------------------------------------------------------------------------
// Kernel 2: combiner. One block per batch element, 320 threads = 5 waves,
// LDS ~1KB (co-residency unconstrained).
//   wave0 lane<60 : W_zh row (100 regs) -> hcomb; streams h_rev[t] from global
//   waves1-4      : pair p=(wv-1)*32+(lane>>1) (p<100); even lane: W_hl[p],
//                   odd lane: W_hs[p] (60 regs); sc swapped via shfl_xor(1).
// 2 barriers per step.
// ---------------------------------------------------------------------------
__global__ __launch_bounds__(320, 1)
void comb_kernel(const float* __restrict__ eps,   // [T][B][Z]
                 const float* __restrict__ zq0,
                 const float* __restrict__ W_zh,  // [H][Z]
                 const float* __restrict__ b_zh,
                 const float* __restrict__ W_hl,  // [Z][H]
                 const float* __restrict__ b_hl,
                 const float* __restrict__ W_hs,  // [Z][H]
                 const float* __restrict__ b_hs,
                 const float* __restrict__ hrev,  // [B][T][H] (ws)
                 float* __restrict__ out)
{
    __shared__ __align__(16) float zbuf[NZ];
    __shared__ __align__(16) float hcomb[NH];

    const int b    = blockIdx.x;
    const int tid  = threadIdx.x;
    const int wave = tid >> 6;
    const int lane = tid & 63;

    float w[NZ];          // wave0 uses [0:100); output waves use [0:60)
    float bias = 0.f;
    const int  p      = (wave - 1) * 32 + (lane >> 1);
    const bool outln  = (wave > 0) && (p < NZ);
    const bool evenln = ((lane & 1) == 0);

    const float* hrow = hrev + (size_t)b * NT * NH;
    float hr = 0.f, e_cur = 0.f;

    if (wave == 0) {
        if (lane < NH) {
            const float4* q = reinterpret_cast<const float4*>(W_zh + lane * NZ);
#pragma unroll
            for (int k = 0; k < NZ / 4; ++k) {
                float4 v = q[k];
                w[4*k+0] = v.x; w[4*k+1] = v.y; w[4*k+2] = v.z; w[4*k+3] = v.w;
            }
            bias = b_zh[lane];
            hr   = hrow[lane];                       // h_rev[0]
        }
    } else if (outln) {
        const float* row = evenln ? (W_hl + p * NH) : (W_hs + p * NH);
        const float4* q = reinterpret_cast<const float4*>(row);
#pragma unroll
        for (int k = 0; k < NH / 4; ++k) {
            float4 v = q[k];
            w[4*k+0] = v.x; w[4*k+1] = v.y; w[4*k+2] = v.z; w[4*k+3] = v.w;
        }
        bias = evenln ? b_hl[p] : b_hs[p];
        if (evenln) {
            zbuf[p]  = zq0[p];
            e_cur    = eps[(size_t)b * NZ + p];      // eps[0][b][p]
        }
    }
    __syncthreads();

    float* out_z = out;
    float* out_l = out + (size_t)NB * NT * NZ;
    float* out_s = out + (size_t)2 * NB * NT * NZ;

    for (int t = 0; t < NT; ++t) {
        float e_nxt = 0.f;
        if (wave == 0) {
            float hr_n = (t + 1 < NT && lane < NH) ? hrow[(size_t)(t+1)*NH + lane] : 0.f;
            const float4* z4 = reinterpret_cast<const float4*>(zbuf);
            float a0=0.f,a1=0.f,a2=0.f,a3=0.f, c0=0.f,c1=0.f,c2=0.f,c3=0.f;
#pragma unroll
            for (int k = 0; k < 13; ++k) {
                float4 v = z4[k];
                a0 += v.x*w[4*k+0]; a1 += v.y*w[4*k+1];
                a2 += v.z*w[4*k+2]; a3 += v.w*w[4*k+3];
            }
#pragma unroll
            for (int k = 13; k < 25; ++k) {
                float4 v = z4[k];
                c0 += v.x*w[4*k+0]; c1 += v.y*w[4*k+1];
                c2 += v.z*w[4*k+2]; c3 += v.w*w[4*k+3];
            }
            if (lane < NH) {
                float a = ((a0+c0)+(a1+c1)) + ((a2+c2)+(a3+c3)) + bias;
                hcomb[lane] = 0.5f * (fast_tanh(a) + hr);
            }
            hr = hr_n;
        } else if (outln && evenln && t + 1 < NT) {
            e_nxt = eps[((size_t)(t + 1) * NB + b) * NZ + p];  // overlaps wave0
        }
        __syncthreads();  // hcomb ready; zbuf reads done before overwrite

        if (outln) {
            const float4* h4 = reinterpret_cast<const float4*>(hcomb);
            float c0=0.f,c1=0.f,c2=0.f,c3=0.f, c4=0.f,c5=0.f,c6=0.f,c7=0.f;
#pragma unroll
            for (int k = 0; k < 8; ++k) {
                float4 v = h4[k];
                c0 += v.x*w[4*k+0]; c1 += v.y*w[4*k+1];
                c2 += v.z*w[4*k+2]; c3 += v.w*w[4*k+3];
            }
#pragma unroll
            for (int k = 8; k < 15; ++k) {
                float4 v = h4[k];
                c4 += v.x*w[4*k+0]; c5 += v.y*w[4*k+1];
                c6 += v.z*w[4*k+2]; c7 += v.w*w[4*k+3];
            }
            float s = ((c0+c4)+(c1+c5)) + ((c2+c6)+(c3+c7)) + bias;
            float res = evenln ? s : fast_softplus(s);   // even: loc, odd: sc
            float other = __shfl_xor(res, 1, 64);
            size_t oi = ((size_t)b * NT + t) * NZ + p;
            if (evenln) {
                float zv = res + other * e_cur;          // loc + sc*eps
                out_z[oi] = zv;
                out_l[oi] = res;
                zbuf[p]   = zv;
                e_cur     = e_nxt;
            } else {
                out_s[oi] = res;
            }
        }
        __syncthreads();  // zbuf ready for next step
    }
}

// ---------------------------------------------------------------------------
// Fallback (ws too small): round-1 monolithic kernel (proven, 507us).
// ---------------------------------------------------------------------------
__global__ __launch_bounds__(128, 1)
void encoder_mono(const float* __restrict__ xrev, const int* __restrict__ seqlen,
                  const float* __restrict__ eps,
                  const float* __restrict__ W_ih, const float* __restrict__ W_hh,
                  const float* __restrict__ b_ih, const float* __restrict__ b_hh,
                  const float* __restrict__ h0,   const float* __restrict__ zq0,
                  const float* __restrict__ W_zh, const float* __restrict__ b_zh,
                  const float* __restrict__ W_hl, const float* __restrict__ b_hl,
                  const float* __restrict__ W_hs, const float* __restrict__ b_hs,
                  float* __restrict__ out)
{
    __shared__ __align__(16) float h_rev[NT][NH];
    __shared__ __align__(16) float xbuf[NIN];
    __shared__ __align__(16) float hbuf[NH];
    __shared__ __align__(16) float zbuf[NZ];
    __shared__ __align__(16) float hcomb[NH];

    const int b = blockIdx.x, tid = threadIdx.x;
    const int wave = tid >> 6, lane = tid & 63;
    const int sl = seqlen[b];

    for (int i = tid; i < NT * NH; i += 128) (&h_rev[0][0])[i] = 0.0f;
    __syncthreads();

    if (wave == 0) {
        float wih[NIN], whh[NH];
        float bias = 0.f;
        if (lane < NH) {
            const float4* pp = reinterpret_cast<const float4*>(W_ih + lane * NIN);
#pragma unroll
            for (int k = 0; k < NIN / 4; ++k) {
                float4 v = pp[k];
                wih[4*k+0]=v.x; wih[4*k+1]=v.y; wih[4*k+2]=v.z; wih[4*k+3]=v.w;
            }
            const float4* q = reinterpret_cast<const float4*>(W_hh + lane * NH);
#pragma unroll
            for (int k = 0; k < NH / 4; ++k) {
                float4 v = q[k];
                whh[4*k+0]=v.x; whh[4*k+1]=v.y; whh[4*k+2]=v.z; whh[4*k+3]=v.w;
            }
            bias = b_ih[lane] + b_hh[lane];
            hbuf[lane] = h0[lane];
        } else {
#pragma unroll
            for (int k = 0; k < NIN; ++k) wih[k] = 0.f;
#pragma unroll
            for (int k = 0; k < NH; ++k) whh[k] = 0.f;
        }
        const float* xb = xrev + (size_t)b * NT * NIN;
        float xa = xb[lane];
        float xc = (lane < NIN - 64) ? xb[64 + lane] : 0.f;
        for (int t = 0; t < NT; ++t) {
            xbuf[lane] = xa;
            if (lane < NIN - 64) xbuf[64 + lane] = xc;
            if (t + 1 < NT) {
                xa = xb[(size_t)(t+1)*NIN + lane];
                xc = (lane < NIN - 64) ? xb[(size_t)(t+1)*NIN + 64 + lane] : 0.f;
            }
            float a0=0.f,a1=0.f,a2=0.f,a3=0.f;
            const float4* x4 = reinterpret_cast<const float4*>(xbuf);
#pragma unroll
            for (int k = 0; k < NIN / 4; ++k) {
                float4 v = x4[k];
                a0 += v.x*wih[4*k+0]; a1 += v.y*wih[4*k+1];
                a2 += v.z*wih[4*k+2]; a3 += v.w*wih[4*k+3];
            }
            const float4* h4 = reinterpret_cast<const float4*>(hbuf);
#pragma unroll
            for (int k = 0; k < NH / 4; ++k) {
                float4 v = h4[k];
                a0 += v.x*whh[4*k+0]; a1 += v.y*whh[4*k+1];
                a2 += v.z*whh[4*k+2]; a3 += v.w*whh[4*k+3];
            }
            float hn = fmaxf((a0+a1)+(a2+a3)+bias, 0.f);
            if (lane < NH) {
                hbuf[lane] = hn;
                if (t < sl) h_rev[sl-1-t][lane] = hn;
            }
        }
    }
    __syncthreads();

    const int o = 50 * wave + lane;
    float wzr[NZ]; float bz = 0.f;
    if (wave == 0 && lane < NH) {
        const float4* pp = reinterpret_cast<const float4*>(W_zh + lane * NZ);
#pragma unroll
        for (int k = 0; k < NZ / 4; ++k) {
            float4 v = pp[k];
            wzr[4*k+0]=v.x; wzr[4*k+1]=v.y; wzr[4*k+2]=v.z; wzr[4*k+3]=v.w;
        }
        bz = b_zh[lane];
    } else {
#pragma unroll
        for (int k = 0; k < NZ; ++k) wzr[k] = 0.f;
    }
    float wl[NH], ws_[NH]; float bl = 0.f, bs = 0.f;
    if (lane < 50) {
        const float4* pp = reinterpret_cast<const float4*>(W_hl + o * NH);
        const float4* q  = reinterpret_cast<const float4*>(W_hs + o * NH);
#pragma unroll
        for (int k = 0; k < NH / 4; ++k) {
            float4 v = pp[k];
            wl[4*k+0]=v.x; wl[4*k+1]=v.y; wl[4*k+2]=v.z; wl[4*k+3]=v.w;
            float4 u = q[k];
            ws_[4*k+0]=u.x; ws_[4*k+1]=u.y; ws_[4*k+2]=u.z; ws_[4*k+3]=u.w;
        }
        bl = b_hl[o]; bs = b_hs[o];
        zbuf[o] = zq0[o];
    } else {
#pragma unroll
        for (int k = 0; k < NH; ++k) { wl[k]=0.f; ws_[k]=0.f; }
    }
    __syncthreads();

    float* out_z = out;
    float* out_l = out + (size_t)NB * NT * NZ;
    float* out_s = out + (size_t)2 * NB * NT * NZ;
    const float* epsb = eps + (size_t)b * NZ;
    float e_cur = (lane < 50) ? epsb[o] : 0.f;

    for (int t = 0; t < NT; ++t) {
        if (wave == 0) {
            float a0=0.f,a1=0.f,a2=0.f,a3=0.f;
            const float4* z4 = reinterpret_cast<const float4*>(zbuf);
#pragma unroll
            for (int k = 0; k < NZ / 4; ++k) {
                float4 v = z4[k];
                a0 += v.x*wzr[4*k+0]; a1 += v.y*wzr[4*k+1];
                a2 += v.z*wzr[4*k+2]; a3 += v.w*wzr[4*k+3];
            }
            if (lane < NH) {
                float a = (a0+a1)+(a2+a3)+bz;
                hcomb[lane] = 0.5f * (fast_tanh(a) + h_rev[t][lane]);
            }
        }
        __syncthreads();
        float e_nxt = 0.f;
        if (t + 1 < NT && lane < 50) e_nxt = epsb[(size_t)(t+1)*NB*NZ + o];
        if (lane < 50) {
            float c0=0.f,c1=0.f,c2=0.f,c3=0.f, d0=0.f,d1=0.f,d2=0.f,d3=0.f;
            const float4* h4 = reinterpret_cast<const float4*>(hcomb);
#pragma unroll
            for (int k = 0; k < NH / 4; ++k) {
                float4 v = h4[k];
                c0 += v.x*wl[4*k+0];  c1 += v.y*wl[4*k+1];
                c2 += v.z*wl[4*k+2];  c3 += v.w*wl[4*k+3];
                d0 += v.x*ws_[4*k+0]; d1 += v.y*ws_[4*k+1];
                d2 += v.z*ws_[4*k+2]; d3 += v.w*ws_[4*k+3];
            }
            float loc = (c0+c1)+(c2+c3)+bl;
            float ps  = (d0+d1)+(d2+d3)+bs;
            float sc  = fast_softplus(ps);
            float zv  = loc + sc * e_cur;
            size_t oi = ((size_t)b * NT + t) * NZ + o;
            out_z[oi]=zv; out_l[oi]=loc; out_s[oi]=sc;
            zbuf[o]=zv;
        }
        e_cur = e_nxt;
        __syncthreads();
    }
}

extern "C" void kernel_launch(void* const* d_in, const int* in_sizes, int n_in,
                              void* d_out, int out_size, void* d_ws, size_t ws_size,
                              hipStream_t stream) {
    const float* xrev   = (const float*)d_in[1];
    const int*   seqlen = (const int*)  d_in[3];
    const float* eps    = (const float*)d_in[4];
    const float* W_ih   = (const float*)d_in[5];
    const float* W_hh   = (const float*)d_in[6];
    const float* b_ih   = (const float*)d_in[7];
    const float* b_hh   = (const float*)d_in[8];
    const float* h0     = (const float*)d_in[9];
    const float* zq0    = (const float*)d_in[10];
    const float* W_zh   = (const float*)d_in[11];
    const float* b_zh   = (const float*)d_in[12];
    const float* W_hl   = (const float*)d_in[13];
    const float* b_hl   = (const float*)d_in[14];
    const float* W_hs   = (const float*)d_in[15];
    const float* b_hs   = (const float*)d_in[16];
    float* out = (float*)d_out;

    const size_t hrev_bytes = (size_t)NB * NT * NH * sizeof(float);
    if (ws_size >= hrev_bytes) {
        float* hrev = (float*)d_ws;
        rnn_kernel<<<NB, 64, 0, stream>>>(xrev, seqlen, W_ih, W_hh, b_ih, b_hh,
                                          h0, hrev);
        comb_kernel<<<NB, 320, 0, stream>>>(eps, zq0, W_zh, b_zh,
                                            W_hl, b_hl, W_hs, b_hs, hrev, out);
    } else {
        encoder_mono<<<NB, 128, 0, stream>>>(xrev, seqlen, eps,
                                             W_ih, W_hh, b_ih, b_hh, h0, zq0,
                                             W_zh, b_zh, W_hl, b_hl, W_hs, b_hs,
                                             out);
    }
}